// Round 1
// baseline (301.764 us; speedup 1.0000x reference)
//
#include <hip/hip_runtime.h>
#include <cstdint>
#include <cstddef>

typedef __bf16 bf16;
typedef __bf16 bf16x8 __attribute__((ext_vector_type(8)));
typedef float  f32x4  __attribute__((ext_vector_type(4)));

#define NB 4
#define SS 2048
#define EE 1024

// ---------------------------------------------------------------------------
// Staging helpers: tile is [128 rows][32 k] bf16 in LDS, padded to 40 elems
// (row stride 80 B = 5*16 B, keeps every b128 access 16B-aligned, spreads
// banks so frag reads are ~2-way instead of 8-way on linear [128][32]).
// Each of 256 threads stages 16 elements: row = tid>>1, k-offset (tid&1)*16.
// ---------------------------------------------------------------------------
static __device__ __forceinline__ void stage_f32(bf16 (*lds)[40],
                                                 const float* __restrict__ src,
                                                 int stride, int tid)
{
    const int row = tid >> 1;
    const int ko  = (tid & 1) << 4;
    const float4* p = (const float4*)(src + (size_t)row * stride + ko);
    float4 f0 = p[0], f1 = p[1], f2 = p[2], f3 = p[3];
    bf16x8 h0, h1;
    h0[0] = (bf16)f0.x; h0[1] = (bf16)f0.y; h0[2] = (bf16)f0.z; h0[3] = (bf16)f0.w;
    h0[4] = (bf16)f1.x; h0[5] = (bf16)f1.y; h0[6] = (bf16)f1.z; h0[7] = (bf16)f1.w;
    h1[0] = (bf16)f2.x; h1[1] = (bf16)f2.y; h1[2] = (bf16)f2.z; h1[3] = (bf16)f2.w;
    h1[4] = (bf16)f3.x; h1[5] = (bf16)f3.y; h1[6] = (bf16)f3.z; h1[7] = (bf16)f3.w;
    *(bf16x8*)&lds[row][ko]     = h0;
    *(bf16x8*)&lds[row][ko + 8] = h1;
}

static __device__ __forceinline__ void stage_bf16(bf16 (*lds)[40],
                                                  const bf16* __restrict__ src,
                                                  int stride, int tid)
{
    const int row = tid >> 1;
    const int ko  = (tid & 1) << 4;
    const uint4* p = (const uint4*)(src + (size_t)row * stride + ko);
    uint4 v0 = p[0], v1 = p[1];
    *(uint4*)&lds[row][ko]     = v0;
    *(uint4*)&lds[row][ko + 8] = v1;
}

// ---------------------------------------------------------------------------
// K1: fused QKV projection. C[s][j] = sum_e A[s][e] * W[j][e] + b[j]
// B^T-form GEMM, M=8192 (B*S flattened), N=K=1024. fp32 in, bf16 out.
// blockIdx.z selects q/k/v. 4 waves, each owns a 64x64 quadrant (4x4 frags of
// 16x16x32 MFMA). C/D layout: col = lane&15, row = (lane>>4)*4 + j  [m89/m91].
// ---------------------------------------------------------------------------
__global__ __launch_bounds__(256) void proj_kernel(
    const float* __restrict__ query, const float* __restrict__ key,
    const float* __restrict__ value,
    const float* __restrict__ Wq, const float* __restrict__ bq,
    const float* __restrict__ Wk, const float* __restrict__ bk,
    const float* __restrict__ Wv, const float* __restrict__ bv,
    bf16* __restrict__ qb, bf16* __restrict__ kb, bf16* __restrict__ vb)
{
    __shared__ bf16 la[128][40];
    __shared__ bf16 lb[128][40];

    const float* A; const float* W; const float* bias; bf16* out;
    const int z = blockIdx.z;
    if (z == 0)      { A = query; W = Wq; bias = bq; out = qb; }
    else if (z == 1) { A = key;   W = Wk; bias = bk; out = kb; }
    else             { A = value; W = Wv; bias = bv; out = vb; }

    const int m0 = blockIdx.y * 128;
    const int n0 = blockIdx.x * 128;
    const int tid = threadIdx.x, lane = tid & 63, w = tid >> 6;
    const int wr = (w >> 1) * 64, wc = (w & 1) * 64;
    const int lr = lane & 15, kq = lane >> 4;

    f32x4 zero; zero[0] = 0.f; zero[1] = 0.f; zero[2] = 0.f; zero[3] = 0.f;
    f32x4 acc[4][4];
#pragma unroll
    for (int m = 0; m < 4; ++m)
#pragma unroll
        for (int n = 0; n < 4; ++n) acc[m][n] = zero;

    for (int kt = 0; kt < 1024; kt += 32) {
        stage_f32(la, A + (size_t)m0 * 1024 + kt, 1024, tid);
        stage_f32(lb, W + (size_t)n0 * 1024 + kt, 1024, tid);
        __syncthreads();
        bf16x8 af[4], bfr[4];
#pragma unroll
        for (int m = 0; m < 4; ++m) af[m]  = *(const bf16x8*)&la[wr + m * 16 + lr][kq * 8];
#pragma unroll
        for (int n = 0; n < 4; ++n) bfr[n] = *(const bf16x8*)&lb[wc + n * 16 + lr][kq * 8];
#pragma unroll
        for (int m = 0; m < 4; ++m)
#pragma unroll
            for (int n = 0; n < 4; ++n)
                acc[m][n] = __builtin_amdgcn_mfma_f32_16x16x32_bf16(af[m], bfr[n], acc[m][n], 0, 0, 0);
        __syncthreads();
    }

#pragma unroll
    for (int n = 0; n < 4; ++n) {
        const int gcol = n0 + wc + n * 16 + lr;
        const float bv_ = bias[gcol];
#pragma unroll
        for (int m = 0; m < 4; ++m) {
#pragma unroll
            for (int j = 0; j < 4; ++j) {
                const int grow = m0 + wr + m * 16 + kq * 4 + j;
                out[(size_t)grow * 1024 + gcol] = (bf16)(acc[m][n][j] + bv_);
            }
        }
    }
}

// ---------------------------------------------------------------------------
// K2: vb [b][s][e] -> vt [b][e][s]  (PV GEMM wants V^T in B^T-row form)
// ---------------------------------------------------------------------------
__global__ __launch_bounds__(256) void transpose_kernel(const bf16* __restrict__ vb,
                                                        bf16* __restrict__ vt)
{
    __shared__ bf16 t[64][72];
    const int b  = blockIdx.z;
    const int s0 = blockIdx.x * 64, e0 = blockIdx.y * 64;
    const int tid = threadIdx.x;

    const bf16* src = vb + ((size_t)b * SS + s0) * EE + e0;
#pragma unroll
    for (int i = 0; i < 2; ++i) {
        const int c  = tid * 2 + i;
        const int r  = c >> 3;
        const int cc = (c & 7) * 8;
        *(uint4*)&t[r][cc] = *(const uint4*)&src[(size_t)r * EE + cc];
    }
    __syncthreads();

    bf16* dst = vt + ((size_t)b * EE + e0) * SS + s0;
    const int er  = tid >> 2;
    const int sc0 = (tid & 3) * 16;
    bf16 tmp[16];
#pragma unroll
    for (int k2 = 0; k2 < 16; ++k2) tmp[k2] = t[sc0 + k2][er];
    *(uint4*)&dst[(size_t)er * SS + sc0]     = *(uint4*)&tmp[0];
    *(uint4*)&dst[(size_t)er * SS + sc0 + 8] = *(uint4*)&tmp[8];
}

// ---------------------------------------------------------------------------
// K3: scores[b][s][t] = (q[s] . k[t]) / 32 + mask[b][s][t], stored bf16.
// B^T GEMM per batch: M=N=2048, K=1024.
// ---------------------------------------------------------------------------
__global__ __launch_bounds__(256) void scores_kernel(const bf16* __restrict__ qb,
                                                     const bf16* __restrict__ kb,
                                                     const float* __restrict__ mask,
                                                     bf16* __restrict__ sc)
{
    __shared__ bf16 la[128][40];
    __shared__ bf16 lb[128][40];

    const int b  = blockIdx.z;
    const bf16* A  = qb + (size_t)b * SS * EE;
    const bf16* Bm = kb + (size_t)b * SS * EE;
    const int m0 = blockIdx.y * 128;
    const int n0 = blockIdx.x * 128;
    const int tid = threadIdx.x, lane = tid & 63, w = tid >> 6;
    const int wr = (w >> 1) * 64, wc = (w & 1) * 64;
    const int lr = lane & 15, kq = lane >> 4;

    f32x4 zero; zero[0] = 0.f; zero[1] = 0.f; zero[2] = 0.f; zero[3] = 0.f;
    f32x4 acc[4][4];
#pragma unroll
    for (int m = 0; m < 4; ++m)
#pragma unroll
        for (int n = 0; n < 4; ++n) acc[m][n] = zero;

    for (int kt = 0; kt < 1024; kt += 32) {
        stage_bf16(la, A  + (size_t)m0 * EE + kt, EE, tid);
        stage_bf16(lb, Bm + (size_t)n0 * EE + kt, EE, tid);
        __syncthreads();
        bf16x8 af[4], bfr[4];
#pragma unroll
        for (int m = 0; m < 4; ++m) af[m]  = *(const bf16x8*)&la[wr + m * 16 + lr][kq * 8];
#pragma unroll
        for (int n = 0; n < 4; ++n) bfr[n] = *(const bf16x8*)&lb[wc + n * 16 + lr][kq * 8];
#pragma unroll
        for (int m = 0; m < 4; ++m)
#pragma unroll
            for (int n = 0; n < 4; ++n)
                acc[m][n] = __builtin_amdgcn_mfma_f32_16x16x32_bf16(af[m], bfr[n], acc[m][n], 0, 0, 0);
        __syncthreads();
    }

    const float* mrow = mask + (size_t)b * SS * SS;
    bf16* out = sc + (size_t)b * SS * SS;
    const float scale = 0.03125f;  // 1/sqrt(1024)
#pragma unroll
    for (int m = 0; m < 4; ++m)
#pragma unroll
        for (int n = 0; n < 4; ++n)
#pragma unroll
            for (int j = 0; j < 4; ++j) {
                const int grow = m0 + wr + m * 16 + kq * 4 + j;
                const int gcol = n0 + wc + n * 16 + lr;
                const float v = acc[m][n][j] * scale + mrow[(size_t)grow * SS + gcol];
                out[(size_t)grow * SS + gcol] = (bf16)v;
            }
}

// ---------------------------------------------------------------------------
// K4: row softmax over 2048, in place, bf16 -> bf16 probs. One block per row.
// 256 threads * 8 elems (one uint4 each).
// ---------------------------------------------------------------------------
__global__ __launch_bounds__(256) void softmax_kernel(bf16* __restrict__ sc)
{
    __shared__ float red[4];
    const size_t row = blockIdx.x;
    uint4* rp = (uint4*)(sc + row * (size_t)SS);
    const int tid = threadIdx.x, lane = tid & 63, wid = tid >> 6;

    const uint4 d = rp[tid];
    const unsigned int u[4] = { d.x, d.y, d.z, d.w };
    float f[8];
#pragma unroll
    for (int i = 0; i < 4; ++i) {
        union { unsigned int i_; float f_; } lo, hi;
        lo.i_ = u[i] << 16;
        hi.i_ = u[i] & 0xffff0000u;
        f[2 * i]     = lo.f_;
        f[2 * i + 1] = hi.f_;
    }

    float m = f[0];
#pragma unroll
    for (int i = 1; i < 8; ++i) m = fmaxf(m, f[i]);
#pragma unroll
    for (int o = 32; o > 0; o >>= 1) m = fmaxf(m, __shfl_xor(m, o));
    if (lane == 0) red[wid] = m;
    __syncthreads();
    m = fmaxf(fmaxf(red[0], red[1]), fmaxf(red[2], red[3]));
    __syncthreads();

    float e[8], s = 0.f;
#pragma unroll
    for (int i = 0; i < 8; ++i) { e[i] = __expf(f[i] - m); s += e[i]; }
#pragma unroll
    for (int o = 32; o > 0; o >>= 1) s += __shfl_xor(s, o);
    if (lane == 0) red[wid] = s;
    __syncthreads();
    s = red[0] + red[1] + red[2] + red[3];
    const float inv = 1.0f / s;

    unsigned int ou[4];
#pragma unroll
    for (int i = 0; i < 4; ++i) {
        union { bf16 h; unsigned short b; } a0, a1;
        a0.h = (bf16)(e[2 * i] * inv);
        a1.h = (bf16)(e[2 * i + 1] * inv);
        ou[i] = ((unsigned int)a1.b << 16) | (unsigned int)a0.b;
    }
    rp[tid] = make_uint4(ou[0], ou[1], ou[2], ou[3]);
}

// ---------------------------------------------------------------------------
// K5: out[b][s][e] = sum_t P[b][s][t] * vt[b][e][t].  B^T GEMM per batch:
// M=2048, N=1024, K=2048. fp32 output.
// ---------------------------------------------------------------------------
__global__ __launch_bounds__(256) void pv_kernel(const bf16* __restrict__ sc,
                                                 const bf16* __restrict__ vt,
                                                 float* __restrict__ outp)
{
    __shared__ bf16 la[128][40];
    __shared__ bf16 lb[128][40];

    const int b  = blockIdx.z;
    const bf16* A  = sc + (size_t)b * SS * SS;   // [2048][2048]
    const bf16* Bm = vt + (size_t)b * EE * SS;   // [1024][2048]
    const int m0 = blockIdx.y * 128;
    const int n0 = blockIdx.x * 128;
    const int tid = threadIdx.x, lane = tid & 63, w = tid >> 6;
    const int wr = (w >> 1) * 64, wc = (w & 1) * 64;
    const int lr = lane & 15, kq = lane >> 4;

    f32x4 zero; zero[0] = 0.f; zero[1] = 0.f; zero[2] = 0.f; zero[3] = 0.f;
    f32x4 acc[4][4];
#pragma unroll
    for (int m = 0; m < 4; ++m)
#pragma unroll
        for (int n = 0; n < 4; ++n) acc[m][n] = zero;

    for (int kt = 0; kt < 2048; kt += 32) {
        stage_bf16(la, A  + (size_t)m0 * SS + kt, SS, tid);
        stage_bf16(lb, Bm + (size_t)n0 * SS + kt, SS, tid);
        __syncthreads();
        bf16x8 af[4], bfr[4];
#pragma unroll
        for (int m = 0; m < 4; ++m) af[m]  = *(const bf16x8*)&la[wr + m * 16 + lr][kq * 8];
#pragma unroll
        for (int n = 0; n < 4; ++n) bfr[n] = *(const bf16x8*)&lb[wc + n * 16 + lr][kq * 8];
#pragma unroll
        for (int m = 0; m < 4; ++m)
#pragma unroll
            for (int n = 0; n < 4; ++n)
                acc[m][n] = __builtin_amdgcn_mfma_f32_16x16x32_bf16(af[m], bfr[n], acc[m][n], 0, 0, 0);
        __syncthreads();
    }

#pragma unroll
    for (int m = 0; m < 4; ++m)
#pragma unroll
        for (int n = 0; n < 4; ++n)
#pragma unroll
            for (int j = 0; j < 4; ++j) {
                const int grow = m0 + wr + m * 16 + kq * 4 + j;
                const int gcol = n0 + wc + n * 16 + lr;
                outp[((size_t)b * SS + grow) * EE + gcol] = acc[m][n][j];
            }
}

// ---------------------------------------------------------------------------
// Host launcher
// Inputs: 0 query 1 key 2 value 3 attn_mask 4 Wq 5 bq 6 Wk 7 bk 8 Wv 9 bv
// WS layout (bytes): qb 16.78M | kb 16.78M | vb 16.78M | vt 16.78M | sc 33.55M
// ---------------------------------------------------------------------------
extern "C" void kernel_launch(void* const* d_in, const int* in_sizes, int n_in,
                              void* d_out, int out_size, void* d_ws, size_t ws_size,
                              hipStream_t stream)
{
    const float* query = (const float*)d_in[0];
    const float* key_  = (const float*)d_in[1];
    const float* value = (const float*)d_in[2];
    const float* mask  = (const float*)d_in[3];
    const float* Wq = (const float*)d_in[4];
    const float* bq = (const float*)d_in[5];
    const float* Wk = (const float*)d_in[6];
    const float* bk = (const float*)d_in[7];
    const float* Wv = (const float*)d_in[8];
    const float* bv = (const float*)d_in[9];
    float* outp = (float*)d_out;

    char* ws = (char*)d_ws;
    const size_t QKV = (size_t)NB * SS * EE * 2;       // 16,777,216 B
    const size_t SCB = (size_t)NB * SS * SS * 2;       // 33,554,432 B
    if (ws_size < 4 * QKV + SCB) return;               // would corrupt memory otherwise

    bf16* qb = (bf16*)(ws);
    bf16* kb = (bf16*)(ws + QKV);
    bf16* vb = (bf16*)(ws + 2 * QKV);
    bf16* vt = (bf16*)(ws + 3 * QKV);
    bf16* sc = (bf16*)(ws + 4 * QKV);

    dim3 blk(256);
    proj_kernel<<<dim3(EE / 128, (NB * SS) / 128, 3), blk, 0, stream>>>(
        query, key_, value, Wq, bq, Wk, bk, Wv, bv, qb, kb, vb);
    transpose_kernel<<<dim3(SS / 64, EE / 64, NB), blk, 0, stream>>>(vb, vt);
    scores_kernel<<<dim3(SS / 128, SS / 128, NB), blk, 0, stream>>>(qb, kb, mask, sc);
    softmax_kernel<<<dim3(NB * SS), blk, 0, stream>>>(sc);
    pv_kernel<<<dim3(EE / 128, SS / 128, NB), blk, 0, stream>>>(sc, vt, outp);
}

// Round 2
// 237.209 us; speedup vs baseline: 1.2721x; 1.2721x over previous
//
#include <hip/hip_runtime.h>
#include <cstdint>
#include <cstddef>

typedef __bf16 bf16;
typedef __bf16 bf16x8 __attribute__((ext_vector_type(8)));
typedef float  f32x4  __attribute__((ext_vector_type(4)));

#define NB 4
#define SS 2048
#define EE 1024

// ---------------------------------------------------------------------------
// Async global->LDS, 16 B per lane. LDS dest is wave-uniform base + lane*16
// (m104/m108) so LDS layout must be linear in lane order; global src is
// per-lane.
// ---------------------------------------------------------------------------
static __device__ __forceinline__ void glds16(const bf16* g, void* l)
{
    __builtin_amdgcn_global_load_lds(
        (const __attribute__((address_space(1))) unsigned int*)g,
        (__attribute__((address_space(3))) unsigned int*)l,
        16, 0, 0);
}

// Bijective XCD-aware swizzle (m204). Requires nwg % 8 == 0 (true for all
// GEMM grids here). Consecutive work items on one XCD iterate bx fastest ->
// shared A-panel stays in that XCD's L2.
static __device__ __forceinline__ void swz_block(int& bx, int& by, int& bz)
{
    const int nx = gridDim.x, ny = gridDim.y;
    const int nwg = nx * ny * gridDim.z;
    int lin = blockIdx.x + nx * (blockIdx.y + ny * blockIdx.z);
    const int per = nwg >> 3;
    lin = (lin & 7) * per + (lin >> 3);
    bz = lin / (nx * ny);
    const int r = lin - bz * nx * ny;
    by = r / nx;
    bx = r - by * nx;
}

// ---------------------------------------------------------------------------
// m97-structure K-loop: 128x128 tile, BK=32, linear LDS [128][32] bf16,
// global_load_lds width-16 staging, 2 barriers per K-step.
// 4 waves, each owns a 64x64 quadrant (4x4 frags of 16x16x32 MFMA).
// ---------------------------------------------------------------------------
static __device__ __forceinline__ void gemm_kloop(
    const bf16* __restrict__ A, const bf16* __restrict__ Bm,
    int lda, int ldb, int K,
    bf16* la, bf16* lb,
    int m0, int n0, int tid, int wr, int wc, int lr, int kq,
    f32x4 acc[4][4])
{
    const int srow = tid >> 2;        // 0..63
    const int sko  = (tid & 3) << 3;  // k elem offset: 0,8,16,24
    const int wofs = (tid >> 6) << 10; // per-wave LDS byte offset

    for (int kt = 0; kt < K; kt += 32) {
        // stage A tile: rows m0..m0+127, k kt..kt+31 -> la linear [128][32]
        glds16(A + (size_t)(m0 + srow) * lda + kt + sko,      (char*)la + wofs);
        glds16(A + (size_t)(m0 + 64 + srow) * lda + kt + sko, (char*)la + 4096 + wofs);
        glds16(Bm + (size_t)(n0 + srow) * ldb + kt + sko,      (char*)lb + wofs);
        glds16(Bm + (size_t)(n0 + 64 + srow) * ldb + kt + sko, (char*)lb + 4096 + wofs);
        __syncthreads();  // compiler emits vmcnt(0) drain before barrier

        bf16x8 af[4], bfr[4];
#pragma unroll
        for (int m = 0; m < 4; ++m)
            af[m] = *(const bf16x8*)&la[(wr + m * 16 + lr) * 32 + kq * 8];
#pragma unroll
        for (int n = 0; n < 4; ++n)
            bfr[n] = *(const bf16x8*)&lb[(wc + n * 16 + lr) * 32 + kq * 8];
#pragma unroll
        for (int m = 0; m < 4; ++m)
#pragma unroll
            for (int n = 0; n < 4; ++n)
                acc[m][n] = __builtin_amdgcn_mfma_f32_16x16x32_bf16(af[m], bfr[n], acc[m][n], 0, 0, 0);
        __syncthreads();
    }
}

// ---------------------------------------------------------------------------
// K0: fp32 -> bf16 convert, 8 elems/thread, three tensors via blockIdx.y.
// ---------------------------------------------------------------------------
__global__ __launch_bounds__(256) void cvt3_kernel(
    const float* __restrict__ s0, const float* __restrict__ s1, const float* __restrict__ s2,
    bf16* __restrict__ d0, bf16* __restrict__ d1, bf16* __restrict__ d2, unsigned n)
{
    const float* s; bf16* d;
    if (blockIdx.y == 0)      { s = s0; d = d0; }
    else if (blockIdx.y == 1) { s = s1; d = d1; }
    else                      { s = s2; d = d2; }
    const size_t i = ((size_t)blockIdx.x * 256 + threadIdx.x) * 8;
    if (i >= n) return;
    const float4 f0 = *(const float4*)(s + i);
    const float4 f1 = *(const float4*)(s + i + 4);
    bf16x8 h;
    h[0] = (bf16)f0.x; h[1] = (bf16)f0.y; h[2] = (bf16)f0.z; h[3] = (bf16)f0.w;
    h[4] = (bf16)f1.x; h[5] = (bf16)f1.y; h[6] = (bf16)f1.z; h[7] = (bf16)f1.w;
    *(bf16x8*)(d + i) = h;
}

// ---------------------------------------------------------------------------
// K1: fused QKV projection (bf16 GEMM). C[s][j] = sum_e A[s][e]*W[j][e] + b[j]
// M=8192, N=K=1024, blockIdx.z (swizzled) selects q/k/v.
// C/D layout: col = lane&15, row = (lane>>4)*4 + j  [m89/m91].
// ---------------------------------------------------------------------------
__global__ __launch_bounds__(256) void proj_kernel(
    const bf16* __restrict__ qc, const bf16* __restrict__ kc, const bf16* __restrict__ vc,
    const bf16* __restrict__ Wc,   // [3][1024][1024] bf16
    const float* __restrict__ bq, const float* __restrict__ bk, const float* __restrict__ bv,
    bf16* __restrict__ qb, bf16* __restrict__ kb, bf16* __restrict__ vb)
{
    __shared__ __align__(16) bf16 la[128 * 32];
    __shared__ __align__(16) bf16 lb[128 * 32];

    int bx, by, bz; swz_block(bx, by, bz);
    const bf16* A; const float* bias; bf16* out;
    if (bz == 0)      { A = qc; bias = bq; out = qb; }
    else if (bz == 1) { A = kc; bias = bk; out = kb; }
    else              { A = vc; bias = bv; out = vb; }
    const bf16* Bm = Wc + (size_t)bz * EE * EE;

    const int m0 = by * 128, n0 = bx * 128;
    const int tid = threadIdx.x, lane = tid & 63, w = tid >> 6;
    const int wr = (w >> 1) * 64, wc = (w & 1) * 64;
    const int lr = lane & 15, kq = lane >> 4;

    f32x4 zero; zero[0] = 0.f; zero[1] = 0.f; zero[2] = 0.f; zero[3] = 0.f;
    f32x4 acc[4][4];
#pragma unroll
    for (int m = 0; m < 4; ++m)
#pragma unroll
        for (int n = 0; n < 4; ++n) acc[m][n] = zero;

    gemm_kloop(A, Bm, EE, EE, EE, la, lb, m0, n0, tid, wr, wc, lr, kq, acc);

#pragma unroll
    for (int n = 0; n < 4; ++n) {
        const int gcol = n0 + wc + n * 16 + lr;
        const float bv_ = bias[gcol];
#pragma unroll
        for (int m = 0; m < 4; ++m)
#pragma unroll
            for (int j = 0; j < 4; ++j) {
                const int grow = m0 + wr + m * 16 + kq * 4 + j;
                out[(size_t)grow * EE + gcol] = (bf16)(acc[m][n][j] + bv_);
            }
    }
}

// ---------------------------------------------------------------------------
// K2: vb [b][s][e] -> vt [b][e][s]
// ---------------------------------------------------------------------------
__global__ __launch_bounds__(256) void transpose_kernel(const bf16* __restrict__ vb,
                                                        bf16* __restrict__ vt)
{
    __shared__ bf16 t[64][72];
    const int b  = blockIdx.z;
    const int s0 = blockIdx.x * 64, e0 = blockIdx.y * 64;
    const int tid = threadIdx.x;

    const bf16* src = vb + ((size_t)b * SS + s0) * EE + e0;
#pragma unroll
    for (int i = 0; i < 2; ++i) {
        const int c  = tid * 2 + i;
        const int r  = c >> 3;
        const int cc = (c & 7) * 8;
        *(uint4*)&t[r][cc] = *(const uint4*)&src[(size_t)r * EE + cc];
    }
    __syncthreads();

    bf16* dst = vt + ((size_t)b * EE + e0) * SS + s0;
    const int er  = tid >> 2;
    const int sc0 = (tid & 3) * 16;
    bf16 tmp[16];
#pragma unroll
    for (int k2 = 0; k2 < 16; ++k2) tmp[k2] = t[sc0 + k2][er];
    *(uint4*)&dst[(size_t)er * SS + sc0]     = *(uint4*)&tmp[0];
    *(uint4*)&dst[(size_t)er * SS + sc0 + 8] = *(uint4*)&tmp[8];
}

// ---------------------------------------------------------------------------
// K3: scores[b][s][t] = (q[s].k[t])/32 + mask[b][s][t], bf16 out.
// M=N=2048, K=1024 per batch.
// ---------------------------------------------------------------------------
__global__ __launch_bounds__(256) void scores_kernel(const bf16* __restrict__ qb,
                                                     const bf16* __restrict__ kb,
                                                     const float* __restrict__ mask,
                                                     bf16* __restrict__ sc)
{
    __shared__ __align__(16) bf16 la[128 * 32];
    __shared__ __align__(16) bf16 lb[128 * 32];

    int bx, by, bz; swz_block(bx, by, bz);
    const bf16* A  = qb + (size_t)bz * SS * EE;
    const bf16* Bm = kb + (size_t)bz * SS * EE;

    const int m0 = by * 128, n0 = bx * 128;
    const int tid = threadIdx.x, lane = tid & 63, w = tid >> 6;
    const int wr = (w >> 1) * 64, wc = (w & 1) * 64;
    const int lr = lane & 15, kq = lane >> 4;

    f32x4 zero; zero[0] = 0.f; zero[1] = 0.f; zero[2] = 0.f; zero[3] = 0.f;
    f32x4 acc[4][4];
#pragma unroll
    for (int m = 0; m < 4; ++m)
#pragma unroll
        for (int n = 0; n < 4; ++n) acc[m][n] = zero;

    gemm_kloop(A, Bm, EE, EE, EE, la, lb, m0, n0, tid, wr, wc, lr, kq, acc);

    const float* mrow = mask + (size_t)bz * SS * SS;
    bf16* out = sc + (size_t)bz * SS * SS;
    const float scale = 0.03125f;  // 1/sqrt(1024)
#pragma unroll
    for (int m = 0; m < 4; ++m)
#pragma unroll
        for (int n = 0; n < 4; ++n)
#pragma unroll
            for (int j = 0; j < 4; ++j) {
                const int grow = m0 + wr + m * 16 + kq * 4 + j;
                const int gcol = n0 + wc + n * 16 + lr;
                const float v = acc[m][n][j] * scale + mrow[(size_t)grow * SS + gcol];
                out[(size_t)grow * SS + gcol] = (bf16)v;
            }
}

// ---------------------------------------------------------------------------
// K4: row softmax over 2048, in place, bf16. One block per row.
// ---------------------------------------------------------------------------
__global__ __launch_bounds__(256) void softmax_kernel(bf16* __restrict__ sc)
{
    __shared__ float red[4];
    const size_t row = blockIdx.x;
    uint4* rp = (uint4*)(sc + row * (size_t)SS);
    const int tid = threadIdx.x, lane = tid & 63, wid = tid >> 6;

    const uint4 d = rp[tid];
    const unsigned int u[4] = { d.x, d.y, d.z, d.w };
    float f[8];
#pragma unroll
    for (int i = 0; i < 4; ++i) {
        union { unsigned int i_; float f_; } lo, hi;
        lo.i_ = u[i] << 16;
        hi.i_ = u[i] & 0xffff0000u;
        f[2 * i]     = lo.f_;
        f[2 * i + 1] = hi.f_;
    }

    float m = f[0];
#pragma unroll
    for (int i = 1; i < 8; ++i) m = fmaxf(m, f[i]);
#pragma unroll
    for (int o = 32; o > 0; o >>= 1) m = fmaxf(m, __shfl_xor(m, o));
    if (lane == 0) red[wid] = m;
    __syncthreads();
    m = fmaxf(fmaxf(red[0], red[1]), fmaxf(red[2], red[3]));
    __syncthreads();

    float e[8], s = 0.f;
#pragma unroll
    for (int i = 0; i < 8; ++i) { e[i] = __expf(f[i] - m); s += e[i]; }
#pragma unroll
    for (int o = 32; o > 0; o >>= 1) s += __shfl_xor(s, o);
    if (lane == 0) red[wid] = s;
    __syncthreads();
    s = red[0] + red[1] + red[2] + red[3];
    const float inv = 1.0f / s;

    unsigned int ou[4];
#pragma unroll
    for (int i = 0; i < 4; ++i) {
        union { bf16 h; unsigned short b; } a0, a1;
        a0.h = (bf16)(e[2 * i] * inv);
        a1.h = (bf16)(e[2 * i + 1] * inv);
        ou[i] = ((unsigned int)a1.b << 16) | (unsigned int)a0.b;
    }
    rp[tid] = make_uint4(ou[0], ou[1], ou[2], ou[3]);
}

// ---------------------------------------------------------------------------
// K5: out[b][s][e] = sum_t P[b][s][t] * vt[b][e][t]. M=2048,N=1024,K=2048.
// ---------------------------------------------------------------------------
__global__ __launch_bounds__(256) void pv_kernel(const bf16* __restrict__ sc,
                                                 const bf16* __restrict__ vt,
                                                 float* __restrict__ outp)
{
    __shared__ __align__(16) bf16 la[128 * 32];
    __shared__ __align__(16) bf16 lb[128 * 32];

    int bx, by, bz; swz_block(bx, by, bz);
    const bf16* A  = sc + (size_t)bz * SS * SS;   // [2048][2048]
    const bf16* Bm = vt + (size_t)bz * EE * SS;   // [1024][2048]

    const int m0 = by * 128, n0 = bx * 128;
    const int tid = threadIdx.x, lane = tid & 63, w = tid >> 6;
    const int wr = (w >> 1) * 64, wc = (w & 1) * 64;
    const int lr = lane & 15, kq = lane >> 4;

    f32x4 zero; zero[0] = 0.f; zero[1] = 0.f; zero[2] = 0.f; zero[3] = 0.f;
    f32x4 acc[4][4];
#pragma unroll
    for (int m = 0; m < 4; ++m)
#pragma unroll
        for (int n = 0; n < 4; ++n) acc[m][n] = zero;

    gemm_kloop(A, Bm, SS, SS, SS, la, lb, m0, n0, tid, wr, wc, lr, kq, acc);

#pragma unroll
    for (int m = 0; m < 4; ++m)
#pragma unroll
        for (int n = 0; n < 4; ++n)
#pragma unroll
            for (int j = 0; j < 4; ++j) {
                const int grow = m0 + wr + m * 16 + kq * 4 + j;
                const int gcol = n0 + wc + n * 16 + lr;
                outp[((size_t)bz * SS + grow) * EE + gcol] = acc[m][n][j];
            }
}

// ---------------------------------------------------------------------------
// Host launcher
// Inputs: 0 query 1 key 2 value 3 attn_mask 4 Wq 5 bq 6 Wk 7 bk 8 Wv 9 bv
// WS (bytes): qb | kb | vb | vt | sc | Wc   = 106,954,752 total.
// Aliases (stream-ordered, lifetimes disjoint): qc=vt region; kc,vc=sc region.
// ---------------------------------------------------------------------------
extern "C" void kernel_launch(void* const* d_in, const int* in_sizes, int n_in,
                              void* d_out, int out_size, void* d_ws, size_t ws_size,
                              hipStream_t stream)
{
    const float* query = (const float*)d_in[0];
    const float* key_  = (const float*)d_in[1];
    const float* value = (const float*)d_in[2];
    const float* mask  = (const float*)d_in[3];
    const float* Wq = (const float*)d_in[4];
    const float* bq = (const float*)d_in[5];
    const float* Wk = (const float*)d_in[6];
    const float* bk = (const float*)d_in[7];
    const float* Wv = (const float*)d_in[8];
    const float* bv = (const float*)d_in[9];
    float* outp = (float*)d_out;

    char* ws = (char*)d_ws;
    const size_t QKV = (size_t)NB * SS * EE * 2;   // 16,777,216 B
    const size_t SCB = (size_t)NB * SS * SS * 2;   // 33,554,432 B
    const size_t WCB = (size_t)3 * EE * EE * 2;    //  6,291,456 B
    if (ws_size < 4 * QKV + SCB + WCB) return;

    bf16* qb = (bf16*)(ws);
    bf16* kb = (bf16*)(ws + QKV);
    bf16* vb = (bf16*)(ws + 2 * QKV);
    bf16* vt = (bf16*)(ws + 3 * QKV);
    bf16* sc = (bf16*)(ws + 4 * QKV);
    bf16* Wc = (bf16*)(ws + 4 * QKV + SCB);
    // aliases: converted inputs live only until proj_kernel completes
    bf16* qc = vt;                       // overwritten later by transpose
    bf16* kc = sc;                       // overwritten later by scores
    bf16* vc = (bf16*)(ws + 5 * QKV);    // second half of sc region

    dim3 blk(256);
    const unsigned NQKV = (unsigned)NB * SS * EE;  // 8,388,608
    const unsigned NW   = (unsigned)EE * EE;       // 1,048,576
    cvt3_kernel<<<dim3(NQKV / (256 * 8), 3), blk, 0, stream>>>(
        query, key_, value, qc, kc, vc, NQKV);
    cvt3_kernel<<<dim3(NW / (256 * 8), 3), blk, 0, stream>>>(
        Wq, Wk, Wv, Wc, Wc + (size_t)EE * EE, Wc + 2 * (size_t)EE * EE, NW);

    proj_kernel<<<dim3(EE / 128, (NB * SS) / 128, 3), blk, 0, stream>>>(
        qc, kc, vc, Wc, bq, bk, bv, qb, kb, vb);
    transpose_kernel<<<dim3(SS / 64, EE / 64, NB), blk, 0, stream>>>(vb, vt);
    scores_kernel<<<dim3(SS / 128, SS / 128, NB), blk, 0, stream>>>(qb, kb, mask, sc);
    softmax_kernel<<<dim3(NB * SS), blk, 0, stream>>>(sc);
    pv_kernel<<<dim3(EE / 128, SS / 128, NB), blk, 0, stream>>>(sc, vt, outp);
}

// Round 3
// 195.968 us; speedup vs baseline: 1.5399x; 1.2104x over previous
//
#include <hip/hip_runtime.h>
#include <cstdint>
#include <cstddef>

typedef __bf16 bf16;
typedef __bf16 bf16x8 __attribute__((ext_vector_type(8)));
typedef float  f32x4  __attribute__((ext_vector_type(4)));

#define NB 4
#define SS 2048
#define EE 1024

// LDS buffer: A-tile 128x64 bf16 (16 KB) + B-tile 256x64 bf16 (32 KB)
#define BUFB      49152
#define LDS_TOTAL (3 * BUFB)   // 147456 B, 1 block/CU

// ---------------------------------------------------------------------------
// Async global->LDS, 16 B/lane. LDS dest = wave-uniform base + lane*16
// (m104/m108); global src is per-lane (pre-swizzle happens on the src side).
// ---------------------------------------------------------------------------
static __device__ __forceinline__ void glds16(const bf16* g, void* l)
{
    __builtin_amdgcn_global_load_lds(
        (const __attribute__((address_space(1))) unsigned int*)g,
        (__attribute__((address_space(3))) unsigned int*)l,
        16, 0, 0);
}

// Bijective XCD-aware swizzle (m204-safe: all grids here have nwg % 8 == 0).
static __device__ __forceinline__ void swz_block(int& bx, int& by, int& bz)
{
    const int nx = gridDim.x, ny = gridDim.y;
    const int nwg = nx * ny * gridDim.z;
    int lin = blockIdx.x + nx * (blockIdx.y + ny * blockIdx.z);
    const int per = nwg >> 3;
    lin = (lin & 7) * per + (lin >> 3);
    bz = lin / (nx * ny);
    const int r = lin - bz * nx * ny;
    by = r / nx;
    bx = r - by * nx;
}

// ---------------------------------------------------------------------------
// Pipelined K-loop. BM=128 (m0), BN=256 (n0), BK=64, 512 threads = 8 waves
// (2M x 4N, per-wave 64x64 = 4x4 frags of 16x16x32 bf16 MFMA).
//
// LDS tiles are stored with XOR swizzle: physical_byte = logical ^ ((row&7)<<4)
// (row stride 128 B). Staging keeps the LDS dest linear and applies the
// inverse (= same) permutation to the GLOBAL source address (rule 21).
// Frag ds_reads apply the same XOR -> 16-lane groups spread over all 32 banks
// at 2-way (free, m136).
//
// Pipeline: while computing tile t from buf[t%3], stage tile t+2 into
// buf[(t+2)%3] (6 glds16/thread/tile: A i0,i1 + B i0 in phase 1; B i1..i3 in
// phase 2). Tile boundary: s_waitcnt vmcnt(6) -> tile t+1's 6 loads landed,
// t+2's 6 remain in flight (T4: never drain), then raw s_barrier. WAR-safe:
// buf[(t+2)%3]'s last readers (tile t-1) finished before tile t's barrier.
// ---------------------------------------------------------------------------
static __device__ __forceinline__ void kloop(
    const bf16* __restrict__ A, const bf16* __restrict__ Bm,
    int lda, int ldb, int nt, char* lds, int m0, int n0, int tid,
    f32x4 acc[4][4])
{
    const int lane = tid & 63, w = tid >> 6;
    const int wm = w >> 2, wn = w & 3;
    const int lr = lane & 15, kq = lane >> 4;
    const int axor = (lr & 7) << 4;

    // staging: thread covers physical bytes [tid*16) of each 8 KB issue.
    // physical row r = issue*64 + (tid>>3); physical chunk = tid&7;
    // logical chunk = (tid&7) ^ (r&7)  (r&7 == (tid>>3)&7 since issue*64%8==0)
    const int srow   = tid >> 3;
    const int chunkL = (tid & 7) ^ (srow & 7);
    const bf16* Asrc = A  + (size_t)(m0 + srow) * lda + chunkL * 8;
    const bf16* Bsrc = Bm + (size_t)(n0 + srow) * ldb + chunkL * 8;
    const int wofs = w << 10;   // wave-uniform LDS offset (64 lanes * 16 B)

    // ---- prologue: stage tile 0 -> buf0, tile 1 -> buf1 (12 loads/thread)
#pragma unroll
    for (int p = 0; p < 2; ++p) {
        char* d = lds + p * BUFB + wofs;
        const int kt = p * 64;
        glds16(Asrc + kt,                        d);
        glds16(Asrc + (size_t)64 * lda + kt,     d + 8192);
        glds16(Bsrc + kt,                        d + 16384);
        glds16(Bsrc + (size_t)64 * ldb + kt,     d + 16384 + 8192);
        glds16(Bsrc + (size_t)128 * ldb + kt,    d + 16384 + 16384);
        glds16(Bsrc + (size_t)192 * ldb + kt,    d + 16384 + 24576);
    }
    asm volatile("s_waitcnt vmcnt(6)" ::: "memory");   // tile 0 landed
    __builtin_amdgcn_sched_barrier(0);
    __builtin_amdgcn_s_barrier();
    __builtin_amdgcn_sched_barrier(0);

    for (int t = 0; t < nt; ++t) {
        char* la = lds + (t % 3) * BUFB;
        char* lb = la + 16384;
        char* sa = lds + ((t + 2) % 3) * BUFB;
        const bool st = (t + 2) < nt;
        const int kt = (t + 2) * 64;

        bf16x8 af[4], bg[4];
        // -------- phase 1: k-slice 0
        {
            const int cb = (kq * 16) ^ axor;
#pragma unroll
            for (int m = 0; m < 4; ++m)
                af[m] = *(const bf16x8*)(la + (wm * 64 + m * 16 + lr) * 128 + cb);
#pragma unroll
            for (int n = 0; n < 4; ++n)
                bg[n] = *(const bf16x8*)(lb + (wn * 64 + n * 16 + lr) * 128 + cb);
            if (st) {
                glds16(Asrc + kt,                    sa + wofs);
                glds16(Asrc + (size_t)64 * lda + kt, sa + 8192 + wofs);
                glds16(Bsrc + kt,                    sa + 16384 + wofs);
            }
            __builtin_amdgcn_s_setprio(1);
#pragma unroll
            for (int m = 0; m < 4; ++m)
#pragma unroll
                for (int n = 0; n < 4; ++n)
                    acc[m][n] = __builtin_amdgcn_mfma_f32_16x16x32_bf16(af[m], bg[n], acc[m][n], 0, 0, 0);
            __builtin_amdgcn_s_setprio(0);
        }
        // -------- phase 2: k-slice 1
        {
            const int cb = (64 + kq * 16) ^ axor;
#pragma unroll
            for (int m = 0; m < 4; ++m)
                af[m] = *(const bf16x8*)(la + (wm * 64 + m * 16 + lr) * 128 + cb);
#pragma unroll
            for (int n = 0; n < 4; ++n)
                bg[n] = *(const bf16x8*)(lb + (wn * 64 + n * 16 + lr) * 128 + cb);
            if (st) {
                glds16(Bsrc + (size_t)64 * ldb + kt,  sa + 16384 + 8192 + wofs);
                glds16(Bsrc + (size_t)128 * ldb + kt, sa + 16384 + 16384 + wofs);
                glds16(Bsrc + (size_t)192 * ldb + kt, sa + 16384 + 24576 + wofs);
            }
            __builtin_amdgcn_s_setprio(1);
#pragma unroll
            for (int m = 0; m < 4; ++m)
#pragma unroll
                for (int n = 0; n < 4; ++n)
                    acc[m][n] = __builtin_amdgcn_mfma_f32_16x16x32_bf16(af[m], bg[n], acc[m][n], 0, 0, 0);
            __builtin_amdgcn_s_setprio(0);
        }
        // -------- tile boundary (counted vmcnt, never 0 while staging)
        if (t < nt - 1) {
            if (st) { asm volatile("s_waitcnt vmcnt(6)" ::: "memory"); }
            else    { asm volatile("s_waitcnt vmcnt(0)" ::: "memory"); }
            __builtin_amdgcn_sched_barrier(0);
            __builtin_amdgcn_s_barrier();
            __builtin_amdgcn_sched_barrier(0);
        }
    }
}

// ---------------------------------------------------------------------------
// K0: fp32 -> bf16 convert, 8 elems/thread, three tensors via blockIdx.y.
// ---------------------------------------------------------------------------
__global__ __launch_bounds__(256) void cvt3_kernel(
    const float* __restrict__ s0, const float* __restrict__ s1, const float* __restrict__ s2,
    bf16* __restrict__ d0, bf16* __restrict__ d1, bf16* __restrict__ d2, unsigned n)
{
    const float* s; bf16* d;
    if (blockIdx.y == 0)      { s = s0; d = d0; }
    else if (blockIdx.y == 1) { s = s1; d = d1; }
    else                      { s = s2; d = d2; }
    const size_t i = ((size_t)blockIdx.x * 256 + threadIdx.x) * 8;
    if (i >= n) return;
    const float4 f0 = *(const float4*)(s + i);
    const float4 f1 = *(const float4*)(s + i + 4);
    bf16x8 h;
    h[0] = (bf16)f0.x; h[1] = (bf16)f0.y; h[2] = (bf16)f0.z; h[3] = (bf16)f0.w;
    h[4] = (bf16)f1.x; h[5] = (bf16)f1.y; h[6] = (bf16)f1.z; h[7] = (bf16)f1.w;
    *(bf16x8*)(d + i) = h;
}

// ---------------------------------------------------------------------------
// K1: fused QKV projection. M=8192, N=K=1024, z selects q/k/v.
// C/D 16x16 layout: col = lane&15, row = (lane>>4)*4 + j  [m89/m91].
// ---------------------------------------------------------------------------
__global__ __launch_bounds__(512) void proj8(
    const bf16* __restrict__ qc, const bf16* __restrict__ kc, const bf16* __restrict__ vc,
    const bf16* __restrict__ Wc,
    const float* __restrict__ bq, const float* __restrict__ bk, const float* __restrict__ bv,
    bf16* __restrict__ qb, bf16* __restrict__ kb, bf16* __restrict__ vb)
{
    extern __shared__ char lds[];
    int bx, by, bz; swz_block(bx, by, bz);
    const bf16* A; const float* bias; bf16* out;
    if (bz == 0)      { A = qc; bias = bq; out = qb; }
    else if (bz == 1) { A = kc; bias = bk; out = kb; }
    else              { A = vc; bias = bv; out = vb; }
    const bf16* Bm = Wc + (size_t)bz * EE * EE;

    const int m0 = by * 128, n0 = bx * 256;
    const int tid = threadIdx.x;

    f32x4 acc[4][4];
#pragma unroll
    for (int m = 0; m < 4; ++m)
#pragma unroll
        for (int n = 0; n < 4; ++n) { acc[m][n][0] = 0.f; acc[m][n][1] = 0.f; acc[m][n][2] = 0.f; acc[m][n][3] = 0.f; }

    kloop(A, Bm, EE, EE, EE / 64, lds, m0, n0, tid, acc);

    const int lane = tid & 63, w = tid >> 6, wm = w >> 2, wn = w & 3;
    const int lr = lane & 15, kq = lane >> 4;
#pragma unroll
    for (int n = 0; n < 4; ++n) {
        const int gcol = n0 + wn * 64 + n * 16 + lr;
        const float bb = bias[gcol];
#pragma unroll
        for (int m = 0; m < 4; ++m)
#pragma unroll
            for (int j = 0; j < 4; ++j) {
                const int grow = m0 + wm * 64 + m * 16 + kq * 4 + j;
                out[(size_t)grow * EE + gcol] = (bf16)(acc[m][n][j] + bb);
            }
    }
}

// ---------------------------------------------------------------------------
// K2: vb [b][s][e] -> vt [b][e][s]
// ---------------------------------------------------------------------------
__global__ __launch_bounds__(256) void transpose_kernel(const bf16* __restrict__ vb,
                                                        bf16* __restrict__ vt)
{
    __shared__ bf16 t[64][72];
    const int b  = blockIdx.z;
    const int s0 = blockIdx.x * 64, e0 = blockIdx.y * 64;
    const int tid = threadIdx.x;

    const bf16* src = vb + ((size_t)b * SS + s0) * EE + e0;
#pragma unroll
    for (int i = 0; i < 2; ++i) {
        const int c  = tid * 2 + i;
        const int r  = c >> 3;
        const int cc = (c & 7) * 8;
        *(uint4*)&t[r][cc] = *(const uint4*)&src[(size_t)r * EE + cc];
    }
    __syncthreads();

    bf16* dst = vt + ((size_t)b * EE + e0) * SS + s0;
    const int er  = tid >> 2;
    const int sc0 = (tid & 3) * 16;
    bf16 tmp[16];
#pragma unroll
    for (int k2 = 0; k2 < 16; ++k2) tmp[k2] = t[sc0 + k2][er];
    *(uint4*)&dst[(size_t)er * SS + sc0]     = *(uint4*)&tmp[0];
    *(uint4*)&dst[(size_t)er * SS + sc0 + 8] = *(uint4*)&tmp[8];
}

// ---------------------------------------------------------------------------
// K3: scores = (q.k)/32 + mask, bf16 out. M=2048 (s), N=2048 (t), K=1024.
// ---------------------------------------------------------------------------
__global__ __launch_bounds__(512) void scores8(const bf16* __restrict__ qb,
                                               const bf16* __restrict__ kb,
                                               const float* __restrict__ mask,
                                               bf16* __restrict__ sc)
{
    extern __shared__ char lds[];
    int bx, by, bz; swz_block(bx, by, bz);
    const bf16* A  = qb + (size_t)bz * SS * EE;
    const bf16* Bm = kb + (size_t)bz * SS * EE;

    const int m0 = by * 128, n0 = bx * 256;
    const int tid = threadIdx.x;

    f32x4 acc[4][4];
#pragma unroll
    for (int m = 0; m < 4; ++m)
#pragma unroll
        for (int n = 0; n < 4; ++n) { acc[m][n][0] = 0.f; acc[m][n][1] = 0.f; acc[m][n][2] = 0.f; acc[m][n][3] = 0.f; }

    kloop(A, Bm, EE, EE, EE / 64, lds, m0, n0, tid, acc);

    const int lane = tid & 63, w = tid >> 6, wm = w >> 2, wn = w & 3;
    const int lr = lane & 15, kq = lane >> 4;
    const float* mrow = mask + (size_t)bz * SS * SS;
    bf16* out = sc + (size_t)bz * SS * SS;
    const float scale = 0.03125f;  // 1/sqrt(1024)
#pragma unroll
    for (int m = 0; m < 4; ++m)
#pragma unroll
        for (int n = 0; n < 4; ++n)
#pragma unroll
            for (int j = 0; j < 4; ++j) {
                const int grow = m0 + wm * 64 + m * 16 + kq * 4 + j;
                const int gcol = n0 + wn * 64 + n * 16 + lr;
                const float v = acc[m][n][j] * scale + mrow[(size_t)grow * SS + gcol];
                out[(size_t)grow * SS + gcol] = (bf16)v;
            }
}

// ---------------------------------------------------------------------------
// K4: row softmax over 2048, in place, bf16. One block per row.
// ---------------------------------------------------------------------------
__global__ __launch_bounds__(256) void softmax_kernel(bf16* __restrict__ sc)
{
    __shared__ float red[4];
    const size_t row = blockIdx.x;
    uint4* rp = (uint4*)(sc + row * (size_t)SS);
    const int tid = threadIdx.x, lane = tid & 63, wid = tid >> 6;

    const uint4 d = rp[tid];
    const unsigned int u[4] = { d.x, d.y, d.z, d.w };
    float f[8];
#pragma unroll
    for (int i = 0; i < 4; ++i) {
        union { unsigned int i_; float f_; } lo, hi;
        lo.i_ = u[i] << 16;
        hi.i_ = u[i] & 0xffff0000u;
        f[2 * i]     = lo.f_;
        f[2 * i + 1] = hi.f_;
    }

    float m = f[0];
#pragma unroll
    for (int i = 1; i < 8; ++i) m = fmaxf(m, f[i]);
#pragma unroll
    for (int o = 32; o > 0; o >>= 1) m = fmaxf(m, __shfl_xor(m, o));
    if (lane == 0) red[wid] = m;
    __syncthreads();
    m = fmaxf(fmaxf(red[0], red[1]), fmaxf(red[2], red[3]));
    __syncthreads();

    float e[8], s = 0.f;
#pragma unroll
    for (int i = 0; i < 8; ++i) { e[i] = __expf(f[i] - m); s += e[i]; }
#pragma unroll
    for (int o = 32; o > 0; o >>= 1) s += __shfl_xor(s, o);
    if (lane == 0) red[wid] = s;
    __syncthreads();
    s = red[0] + red[1] + red[2] + red[3];
    const float inv = 1.0f / s;

    unsigned int ou[4];
#pragma unroll
    for (int i = 0; i < 4; ++i) {
        union { bf16 h; unsigned short b; } a0, a1;
        a0.h = (bf16)(e[2 * i] * inv);
        a1.h = (bf16)(e[2 * i + 1] * inv);
        ou[i] = ((unsigned int)a1.b << 16) | (unsigned int)a0.b;
    }
    rp[tid] = make_uint4(ou[0], ou[1], ou[2], ou[3]);
}

// ---------------------------------------------------------------------------
// K5: out = P @ V^T. M=2048 (s), N=1024 (e), K=2048 (t). fp32 out.
// ---------------------------------------------------------------------------
__global__ __launch_bounds__(512) void pv8(const bf16* __restrict__ sc,
                                           const bf16* __restrict__ vt,
                                           float* __restrict__ outp)
{
    extern __shared__ char lds[];
    int bx, by, bz; swz_block(bx, by, bz);
    const bf16* A  = sc + (size_t)bz * SS * SS;   // [2048][2048]
    const bf16* Bm = vt + (size_t)bz * EE * SS;   // [1024][2048]

    const int m0 = by * 128, n0 = bx * 256;
    const int tid = threadIdx.x;

    f32x4 acc[4][4];
#pragma unroll
    for (int m = 0; m < 4; ++m)
#pragma unroll
        for (int n = 0; n < 4; ++n) { acc[m][n][0] = 0.f; acc[m][n][1] = 0.f; acc[m][n][2] = 0.f; acc[m][n][3] = 0.f; }

    kloop(A, Bm, SS, SS, SS / 64, lds, m0, n0, tid, acc);

    const int lane = tid & 63, w = tid >> 6, wm = w >> 2, wn = w & 3;
    const int lr = lane & 15, kq = lane >> 4;
#pragma unroll
    for (int m = 0; m < 4; ++m)
#pragma unroll
        for (int n = 0; n < 4; ++n)
#pragma unroll
            for (int j = 0; j < 4; ++j) {
                const int grow = m0 + wm * 64 + m * 16 + kq * 4 + j;
                const int gcol = n0 + wn * 64 + n * 16 + lr;
                outp[((size_t)bz * SS + grow) * EE + gcol] = acc[m][n][j];
            }
}

// ---------------------------------------------------------------------------
// Host launcher
// Inputs: 0 query 1 key 2 value 3 attn_mask 4 Wq 5 bq 6 Wk 7 bk 8 Wv 9 bv
// WS: qb | kb | vb | vt | sc | Wc. Aliases: qc=vt, kc=sc[0:], vc=sc[half:].
// ---------------------------------------------------------------------------
extern "C" void kernel_launch(void* const* d_in, const int* in_sizes, int n_in,
                              void* d_out, int out_size, void* d_ws, size_t ws_size,
                              hipStream_t stream)
{
    const float* query = (const float*)d_in[0];
    const float* key_  = (const float*)d_in[1];
    const float* value = (const float*)d_in[2];
    const float* mask  = (const float*)d_in[3];
    const float* Wq = (const float*)d_in[4];
    const float* bq = (const float*)d_in[5];
    const float* Wk = (const float*)d_in[6];
    const float* bk = (const float*)d_in[7];
    const float* Wv = (const float*)d_in[8];
    const float* bv = (const float*)d_in[9];
    float* outp = (float*)d_out;

    char* ws = (char*)d_ws;
    const size_t QKV = (size_t)NB * SS * EE * 2;   // 16,777,216 B
    const size_t SCB = (size_t)NB * SS * SS * 2;   // 33,554,432 B
    const size_t WCB = (size_t)3 * EE * EE * 2;    //  6,291,456 B
    if (ws_size < 4 * QKV + SCB + WCB) return;

    bf16* qb = (bf16*)(ws);
    bf16* kb = (bf16*)(ws + QKV);
    bf16* vb = (bf16*)(ws + 2 * QKV);
    bf16* vt = (bf16*)(ws + 3 * QKV);
    bf16* sc = (bf16*)(ws + 4 * QKV);
    bf16* Wc = (bf16*)(ws + 4 * QKV + SCB);
    bf16* qc = vt;                       // lifetime ends before transpose
    bf16* kc = sc;                       // lifetime ends before scores
    bf16* vc = (bf16*)(ws + 5 * QKV);

    // allow 144 KB dynamic LDS on the GEMM kernels (idempotent, capture-safe)
    (void)hipFuncSetAttribute((const void*)proj8,   hipFuncAttributeMaxDynamicSharedMemorySize, LDS_TOTAL);
    (void)hipFuncSetAttribute((const void*)scores8, hipFuncAttributeMaxDynamicSharedMemorySize, LDS_TOTAL);
    (void)hipFuncSetAttribute((const void*)pv8,     hipFuncAttributeMaxDynamicSharedMemorySize, LDS_TOTAL);

    dim3 blk(256), blk5(512);
    const unsigned NQKV = (unsigned)NB * SS * EE;  // 8,388,608
    const unsigned NW   = (unsigned)EE * EE;       // 1,048,576
    cvt3_kernel<<<dim3(NQKV / (256 * 8), 3), blk, 0, stream>>>(
        query, key_, value, qc, kc, vc, NQKV);
    cvt3_kernel<<<dim3(NW / (256 * 8), 3), blk, 0, stream>>>(
        Wq, Wk, Wv, Wc, Wc + (size_t)EE * EE, Wc + 2 * (size_t)EE * EE, NW);

    proj8<<<dim3(EE / 256, (NB * SS) / 128, 3), blk5, LDS_TOTAL, stream>>>(
        qc, kc, vc, Wc, bq, bk, bv, qb, kb, vb);
    transpose_kernel<<<dim3(SS / 64, EE / 64, NB), blk, 0, stream>>>(vb, vt);
    scores8<<<dim3(SS / 256, SS / 128, NB), blk5, LDS_TOTAL, stream>>>(qb, kb, mask, sc);
    softmax_kernel<<<dim3(NB * SS), blk, 0, stream>>>(sc);
    pv8<<<dim3(EE / 256, SS / 128, NB), blk5, LDS_TOTAL, stream>>>(sc, vt, outp);
}